// Round 1
// baseline (177.940 us; speedup 1.0000x reference)
//
#include <hip/hip_runtime.h>
#include <hip/hip_bf16.h>
#include <math.h>

typedef __attribute__((ext_vector_type(8))) short short8;
typedef __attribute__((ext_vector_type(4))) float f32x4;
typedef __attribute__((ext_vector_type(4))) unsigned short us4;

#define DM 1024
#define NH 16
#define DH 64
#define BB 4
#define SS 1024
#define MM 4096
#define NN 3072
#define SCALE 0.125f

__device__ __forceinline__ unsigned short f2b(float f){
    unsigned int u = __float_as_uint(f);
    u += 0x7fffu + ((u >> 16) & 1u);
    return (unsigned short)(u >> 16);
}

// ---- cast fp32 -> bf16, 4 elems/thread ----
__global__ __launch_bounds__(256) void cast_f32_bf16_k(const float* __restrict__ in,
                                                       unsigned short* __restrict__ out){
    int i = (blockIdx.x * 256 + threadIdx.x) * 4;
    float4 v = *(const float4*)(in + i);
    us4 o = { f2b(v.x), f2b(v.y), f2b(v.z), f2b(v.w) };
    *(us4*)(out + i) = o;
}

// ---- transpose + cast W -> wT[proj*1024 + o][k] (bf16) ----
__global__ __launch_bounds__(256) void transpose_cast_w_k(const float* __restrict__ Wq,
                                                          const float* __restrict__ Wk,
                                                          const float* __restrict__ Wv,
                                                          unsigned short* __restrict__ wT){
    __shared__ float tile[32][33];
    const float* W = blockIdx.z==0 ? Wq : (blockIdx.z==1 ? Wk : Wv);
    int o0 = blockIdx.x*32, k0 = blockIdx.y*32;
    int tx = threadIdx.x, ty = threadIdx.y;
    #pragma unroll
    for (int i=0;i<32;i+=8) tile[ty+i][tx] = W[(k0+ty+i)*DM + o0+tx];
    __syncthreads();
    #pragma unroll
    for (int i=0;i<32;i+=8) wT[(blockIdx.z*DM + o0+ty+i)*DM + k0+tx] = f2b(tile[tx][ty+i]);
}

// ---- QKV GEMM: [4096,1024] x [1024,3072] + bias -> Q/K/V bf16 [b][h][s][d] ----
__global__ __launch_bounds__(256) void gemm_qkv_k(
    const unsigned short* __restrict__ xb, const unsigned short* __restrict__ wT,
    const float* __restrict__ bq, const float* __restrict__ bk, const float* __restrict__ bv,
    unsigned short* __restrict__ Qb, unsigned short* __restrict__ Kb, unsigned short* __restrict__ Vb)
{
    __shared__ unsigned short lda[128*32];
    __shared__ unsigned short ldb[128*32];
    const int tid = threadIdx.x;
    const int lane = tid & 63, w = tid >> 6;
    const int wr = w >> 1, wc = w & 1;
    const int lr = lane & 15, lk = (lane >> 4) * 8;
    const int m0 = blockIdx.y * 128, n0 = blockIdx.x * 128;
    f32x4 acc[4][4] = {};
    for (int k0 = 0; k0 < DM; k0 += 32){
        #pragma unroll
        for (int p=0;p<2;p++){
            int idx = tid + p*256;
            int row = idx >> 2, cc = (idx & 3) * 8;
            *(short8*)(&lda[row*32+cc]) = *(const short8*)(&xb[(m0+row)*DM + k0 + cc]);
            *(short8*)(&ldb[row*32+cc]) = *(const short8*)(&wT[(n0+row)*DM + k0 + cc]);
        }
        __syncthreads();
        short8 a[4], b[4];
        #pragma unroll
        for (int m=0;m<4;m++) a[m] = *(const short8*)(&lda[(wr*64+m*16+lr)*32 + lk]);
        #pragma unroll
        for (int n=0;n<4;n++) b[n] = *(const short8*)(&ldb[(wc*64+n*16+lr)*32 + lk]);
        #pragma unroll
        for (int m=0;m<4;m++)
            #pragma unroll
            for (int n=0;n<4;n++)
                acc[m][n] = __builtin_amdgcn_mfma_f32_16x16x32_bf16(a[m], b[n], acc[m][n], 0,0,0);
        __syncthreads();
    }
    #pragma unroll
    for (int m=0;m<4;m++){
        #pragma unroll
        for (int n=0;n<4;n++){
            int C = n0 + wc*64 + n*16 + lr;
            int proj = C >> 10, hd = C & 1023;
            const float* bias = proj==0 ? bq : (proj==1 ? bk : bv);
            unsigned short* dst = proj==0 ? Qb : (proj==1 ? Kb : Vb);
            float badd = bias[hd];
            int h = hd >> 6, d = hd & 63;
            #pragma unroll
            for (int r=0;r<4;r++){
                int R = m0 + wr*64 + m*16 + (lane>>4)*4 + r;
                int b_ = R >> 10, s = R & 1023;
                dst[(((b_*NH)+h)*SS + s)*DH + d] = f2b(acc[m][n][r] + badd);
            }
        }
    }
}

// ---- fused relative attention: per block one (b,h) and 64 Q-rows ----
__global__ __launch_bounds__(256) void attn_k(
    const unsigned short* __restrict__ Qb, const unsigned short* __restrict__ Kb,
    const unsigned short* __restrict__ Vb, const unsigned short* __restrict__ Erb,
    float* __restrict__ out)
{
    __shared__ unsigned short k_lds[64*64];   // K tile [j][d]
    __shared__ unsigned short vt_lds[64*64];  // V^T tile [d][j]
    __shared__ unsigned short er_lds[128*64]; // Er band [tb][d], zero-filled OOB
    __shared__ float rb_lds[4][16*128];       // per-wave Rband rows
    __shared__ unsigned short p_lds[64*64];   // P bf16 [li][lj]

    const int tid = threadIdx.x, lane = tid & 63, w = tid >> 6;
    const int lr = lane & 15, lk4 = lane >> 4;
    const int bh = blockIdx.x;
    const int i0 = blockIdx.y * 64;
    const unsigned short* q_b = Qb + bh*SS*DH;
    const unsigned short* k_b = Kb + bh*SS*DH;
    const unsigned short* v_b = Vb + bh*SS*DH;

    // Q fragments in registers (A-operand: row = lane&15, k-chunk = (lane>>4)*8)
    short8 qf[2];
    #pragma unroll
    for (int kk=0;kk<2;kk++)
        qf[kk] = *(const short8*)(&q_b[(i0 + w*16 + lr)*DH + kk*32 + lk4*8]);

    f32x4 o_acc[4] = {};
    float m_r[4] = {-INFINITY,-INFINITY,-INFINITY,-INFINITY};
    float l_r[4] = {0.f,0.f,0.f,0.f};
    float* rb = &rb_lds[w][0];

    const int ntiles = i0/64 + 1;
    for (int t=0; t<ntiles; t++){
        const int j0 = t*64;
        __syncthreads();
        // stage K tile + V^T tile
        #pragma unroll
        for (int p=0;p<2;p++){
            int idx = tid + p*256;
            int row = idx >> 3, cc = (idx & 7)*8;
            *(short8*)(&k_lds[row*64+cc]) = *(const short8*)(&k_b[(j0+row)*DH + cc]);
            short8 vv = *(const short8*)(&v_b[(j0+row)*DH + cc]);
            #pragma unroll
            for (int e=0;e<8;e++) vt_lds[(cc+e)*64 + row] = (unsigned short)vv[e];
        }
        // stage Er band: t = t0 + tb, tb in [0,128)
        const int t0 = 960 - i0 + j0;
        #pragma unroll
        for (int p=0;p<4;p++){
            int idx = tid + p*256;
            int row = idx >> 3, cc = (idx & 7)*8;
            int tt = t0 + row;
            short8 ev = {0,0,0,0,0,0,0,0};
            if (tt >= 0 && tt < 1024) ev = *(const short8*)(&Erb[tt*DH + cc]);
            *(short8*)(&er_lds[row*64+cc]) = ev;
        }
        __syncthreads();
        // S = Q K^T (4 col-frags), Rband = Q ErBand^T (8 col-frags)
        f32x4 s_acc[4] = {};
        f32x4 r_acc[8] = {};
        #pragma unroll
        for (int kk=0;kk<2;kk++){
            #pragma unroll
            for (int n=0;n<4;n++){
                short8 kf = *(const short8*)(&k_lds[(n*16+lr)*64 + kk*32 + lk4*8]);
                s_acc[n] = __builtin_amdgcn_mfma_f32_16x16x32_bf16(qf[kk], kf, s_acc[n], 0,0,0);
            }
            #pragma unroll
            for (int n=0;n<8;n++){
                short8 ef = *(const short8*)(&er_lds[(n*16+lr)*64 + kk*32 + lk4*8]);
                r_acc[n] = __builtin_amdgcn_mfma_f32_16x16x32_bf16(qf[kk], ef, r_acc[n], 0,0,0);
            }
        }
        // spill Rband to LDS for the diagonal gather (c' = 63 - li + lj)
        #pragma unroll
        for (int n=0;n<8;n++)
            #pragma unroll
            for (int r=0;r<4;r++)
                rb[(lk4*4+r)*128 + n*16+lr] = r_acc[n][r];
        __syncthreads();
        // scores + online softmax (rows live in 16-lane groups)
        float sv[4][4];
        float mnew[4], sfac[4];
        #pragma unroll
        for (int r=0;r<4;r++){
            int rr = lk4*4 + r;
            int li = w*16 + rr;
            int gi = i0 + li;
            float mx = -INFINITY;
            #pragma unroll
            for (int n=0;n<4;n++){
                int lj = n*16 + lr;
                float s = (s_acc[n][r] + rb[rr*128 + (63 - li + lj)]) * SCALE;
                if (j0 + lj > gi) s = -INFINITY;
                sv[n][r] = s;
                mx = fmaxf(mx, s);
            }
            #pragma unroll
            for (int msk=1; msk<16; msk<<=1) mx = fmaxf(mx, __shfl_xor(mx, msk));
            mnew[r] = fmaxf(m_r[r], mx);
            sfac[r] = __expf(m_r[r] - mnew[r]);
            m_r[r] = mnew[r];
        }
        #pragma unroll
        for (int r=0;r<4;r++){
            float rs = 0.f;
            #pragma unroll
            for (int n=0;n<4;n++){
                float p = __expf(sv[n][r] - mnew[r]);
                rs += p;
                p_lds[(w*16 + lk4*4 + r)*64 + n*16 + lr] = f2b(p);
            }
            #pragma unroll
            for (int msk=1; msk<16; msk<<=1) rs += __shfl_xor(rs, msk);
            l_r[r] = l_r[r]*sfac[r] + rs;
            #pragma unroll
            for (int n=0;n<4;n++) o_acc[n][r] *= sfac[r];
        }
        __syncthreads();
        // O += P V  (A = P from p_lds, B = V from vt_lds)
        #pragma unroll
        for (int kk=0;kk<2;kk++){
            short8 pf = *(const short8*)(&p_lds[(w*16+lr)*64 + kk*32 + lk4*8]);
            #pragma unroll
            for (int n=0;n<4;n++){
                short8 vf = *(const short8*)(&vt_lds[(n*16+lr)*64 + kk*32 + lk4*8]);
                o_acc[n] = __builtin_amdgcn_mfma_f32_16x16x32_bf16(pf, vf, o_acc[n], 0,0,0);
            }
        }
    }
    // epilogue: out[b][i][h*64+d] = O / l
    const int b_ = bh >> 4, h = bh & 15;
    #pragma unroll
    for (int n=0;n<4;n++)
        #pragma unroll
        for (int r=0;r<4;r++){
            int li = w*16 + lk4*4 + r;
            int d = n*16 + lr;
            out[(b_*SS + i0 + li)*DM + h*DH + d] = o_acc[n][r] / l_r[r];
        }
}

extern "C" void kernel_launch(void* const* d_in, const int* in_sizes, int n_in,
                              void* d_out, int out_size, void* d_ws, size_t ws_size,
                              hipStream_t stream)
{
    const float* x  = (const float*)d_in[0];
    const float* Wq = (const float*)d_in[1];
    const float* bq = (const float*)d_in[2];
    const float* Wk = (const float*)d_in[3];
    const float* bk = (const float*)d_in[4];
    const float* Wv = (const float*)d_in[5];
    const float* bv = (const float*)d_in[6];
    const float* Er = (const float*)d_in[7];
    float* out = (float*)d_out;
    char* ws = (char*)d_ws;
    unsigned short* xb  = (unsigned short*)(ws);              // 8 MB   x bf16 [4096][1024]
    unsigned short* wT  = (unsigned short*)(ws + 8388608);    // 6 MB   W^T bf16 [3072][1024]
    unsigned short* erb = (unsigned short*)(ws + 14680064);   // 128 KB Er bf16 [1024][64]
    unsigned short* Qb  = (unsigned short*)(ws + 14811136);   // 8 MB   Q bf16 [b][h][s][d]
    unsigned short* Kb  = (unsigned short*)(ws + 23199744);   // 8 MB
    unsigned short* Vb  = (unsigned short*)(ws + 31588352);   // 8 MB

    cast_f32_bf16_k<<<4096, 256, 0, stream>>>(x, xb);
    cast_f32_bf16_k<<<64, 256, 0, stream>>>(Er, erb);
    transpose_cast_w_k<<<dim3(32,32,3), dim3(32,8), 0, stream>>>(Wq, Wk, Wv, wT);
    gemm_qkv_k<<<dim3(24,32), 256, 0, stream>>>(xb, wT, bq, bk, bv, Qb, Kb, Vb);
    attn_k<<<dim3(64,16), 256, 0, stream>>>(Qb, Kb, Vb, erb, out);
}

// Round 2
// 103.515 us; speedup vs baseline: 1.7190x; 1.7190x over previous
//
#include <hip/hip_runtime.h>
#include <hip/hip_bf16.h>
#include <math.h>

typedef __attribute__((ext_vector_type(8))) short short8;
typedef __attribute__((ext_vector_type(4))) float f32x4;
typedef __attribute__((ext_vector_type(4))) unsigned short us4;

#define DM 1024
#define NH 16
#define DH 64
#define BB 4
#define SS 1024
#define SCALE 0.125f

#define GLDS16(g, l) __builtin_amdgcn_global_load_lds(                      \
    (const __attribute__((address_space(1))) unsigned int*)(g),             \
    (__attribute__((address_space(3))) unsigned int*)(l), 16, 0, 0)

__device__ __forceinline__ unsigned short f2b(float f){
    unsigned int u = __float_as_uint(f);
    u += 0x7fffu + ((u >> 16) & 1u);
    return (unsigned short)(u >> 16);
}
__device__ __forceinline__ float b2f(unsigned short b){
    return __uint_as_float(((unsigned int)b) << 16);
}

// ---- cast fp32 -> bf16, 4 elems/thread ----
__global__ __launch_bounds__(256) void cast_f32_bf16_k(const float* __restrict__ in,
                                                       unsigned short* __restrict__ out){
    int i = (blockIdx.x * 256 + threadIdx.x) * 4;
    float4 v = *(const float4*)(in + i);
    us4 o = { f2b(v.x), f2b(v.y), f2b(v.z), f2b(v.w) };
    *(us4*)(out + i) = o;
}

// ---- transpose + cast W -> wT[proj*1024 + o][k] (bf16) ----
__global__ __launch_bounds__(256) void transpose_cast_w_k(const float* __restrict__ Wq,
                                                          const float* __restrict__ Wk,
                                                          const float* __restrict__ Wv,
                                                          unsigned short* __restrict__ wT){
    __shared__ float tile[32][33];
    const float* W = blockIdx.z==0 ? Wq : (blockIdx.z==1 ? Wk : Wv);
    int o0 = blockIdx.x*32, k0 = blockIdx.y*32;
    int tx = threadIdx.x, ty = threadIdx.y;
    #pragma unroll
    for (int i=0;i<32;i+=8) tile[ty+i][tx] = W[(k0+ty+i)*DM + o0+tx];
    __syncthreads();
    #pragma unroll
    for (int i=0;i<32;i+=8) wT[(blockIdx.z*DM + o0+ty+i)*DM + k0+tx] = f2b(tile[tx][ty+i]);
}

// ---- QKV GEMM: [4096,1024] x [1024,3072] + bias -> Q/K/V bf16 [b][h][s][d] ----
__global__ __launch_bounds__(256) void gemm_qkv_k(
    const unsigned short* __restrict__ xb, const unsigned short* __restrict__ wT,
    const float* __restrict__ bq, const float* __restrict__ bk, const float* __restrict__ bv,
    unsigned short* __restrict__ Qb, unsigned short* __restrict__ Kb, unsigned short* __restrict__ Vb)
{
    __shared__ unsigned short lda[128*32];
    __shared__ unsigned short ldb[128*32];
    const int tid = threadIdx.x;
    const int lane = tid & 63, w = tid >> 6;
    const int wr = w >> 1, wc = w & 1;
    const int lr = lane & 15, lk = (lane >> 4) * 8;
    const int m0 = blockIdx.y * 128, n0 = blockIdx.x * 128;
    f32x4 acc[4][4] = {};
    for (int k0 = 0; k0 < DM; k0 += 32){
        #pragma unroll
        for (int p=0;p<2;p++){
            int idx = tid + p*256;
            int row = idx >> 2, cc = (idx & 3) * 8;
            GLDS16(&xb[(m0+row)*DM + k0 + cc], &lda[idx<<3]);
            GLDS16(&wT[(n0+row)*DM + k0 + cc], &ldb[idx<<3]);
        }
        __syncthreads();
        short8 a[4], b[4];
        #pragma unroll
        for (int m=0;m<4;m++) a[m] = *(const short8*)(&lda[(wr*64+m*16+lr)*32 + lk]);
        #pragma unroll
        for (int n=0;n<4;n++) b[n] = *(const short8*)(&ldb[(wc*64+n*16+lr)*32 + lk]);
        __builtin_amdgcn_s_setprio(1);
        #pragma unroll
        for (int m=0;m<4;m++)
            #pragma unroll
            for (int n=0;n<4;n++)
                acc[m][n] = __builtin_amdgcn_mfma_f32_16x16x32_bf16(a[m], b[n], acc[m][n], 0,0,0);
        __builtin_amdgcn_s_setprio(0);
        __syncthreads();
    }
    #pragma unroll
    for (int m=0;m<4;m++){
        #pragma unroll
        for (int n=0;n<4;n++){
            int C = n0 + wc*64 + n*16 + lr;
            int proj = C >> 10, hd = C & 1023;
            const float* bias = proj==0 ? bq : (proj==1 ? bk : bv);
            unsigned short* dst = proj==0 ? Qb : (proj==1 ? Kb : Vb);
            float badd = bias[hd];
            int h = hd >> 6, d = hd & 63;
            #pragma unroll
            for (int r=0;r<4;r++){
                int R = m0 + wr*64 + m*16 + (lane>>4)*4 + r;
                int b_ = R >> 10, s = R & 1023;
                dst[(((b_*NH)+h)*SS + s)*DH + d] = f2b(acc[m][n][r] + badd);
            }
        }
    }
}

// ---- fused relative attention: per block one (b,h) and 64 Q-rows ----
// All short tiles XOR-swizzled: byte ^= ((row&7)<<4)  (16B-chunk ^= row&7)
__global__ __launch_bounds__(256) void attn_k(
    const unsigned short* __restrict__ Qb, const unsigned short* __restrict__ Kb,
    const unsigned short* __restrict__ Vb, const unsigned short* __restrict__ Erb,
    float* __restrict__ out)
{
    __shared__ unsigned short k_lds[64*64];    // K tile  [j][d]   swizzled
    __shared__ unsigned short vt_lds[64*64];   // V^T tile [d][j]  swizzled
    __shared__ unsigned short er_lds[128*64];  // Er band [c'][d]  swizzled
    __shared__ unsigned short p_lds[64*64];    // P bf16  [li][lj] swizzled
    __shared__ unsigned short rb_lds[4][16*80];// per-wave R rows, bf16, stride 80

    const int tid = threadIdx.x, lane = tid & 63, w = tid >> 6;
    const int lr = lane & 15, lk4 = lane >> 4;
    const int bh = blockIdx.x;
    const int i0 = (int)(gridDim.y - 1 - blockIdx.y) * 64;   // heavy blocks first
    const unsigned short* q_b = Qb + bh*SS*DH;
    const unsigned short* k_b = Kb + bh*SS*DH;
    const unsigned short* v_b = Vb + bh*SS*DH;

    // Q fragments in registers (A-operand: row = lane&15, k-chunk = (lane>>4)*8)
    short8 qf[2];
    #pragma unroll
    for (int kk=0;kk<2;kk++)
        qf[kk] = *(const short8*)(&q_b[(i0 + w*16 + lr)*DH + kk*32 + lk4*8]);

    // V^T column-owner ids
    const int vd = tid & 63, vjg = tid >> 6;

    f32x4 o_acc[4] = {};
    float m_r[4] = {-INFINITY,-INFINITY,-INFINITY,-INFINITY};
    float l_r[4] = {0.f,0.f,0.f,0.f};
    unsigned short* rbw = &rb_lds[w][0];
    const int fbase = 3 - w;            // first Er frag this wave needs

    const int ntiles = i0/64 + 1;
    for (int t=0; t<ntiles; t++){
        const int j0 = t*64;
        const int t0 = 960 - i0 + j0;
        __syncthreads();
        // K tile: async global->LDS, pre-swizzled source
        #pragma unroll
        for (int p=0;p<2;p++){
            int idx = tid + p*256;
            int row = idx >> 3, ch = idx & 7;
            GLDS16(&k_b[(j0+row)*DH + ((ch ^ (row&7))<<3)], &k_lds[idx<<3]);
        }
        // Er band (128 rows, zero-padded source past 1024)
        #pragma unroll
        for (int p=0;p<4;p++){
            int idx = tid + p*256;
            int row = idx >> 3, ch = idx & 7;
            GLDS16(&Erb[(t0+row)*DH + ((ch ^ (row&7))<<3)], &er_lds[idx<<3]);
        }
        // V^T: thread owns column d, gathers 16 j's (coalesced across lanes)
        {
            unsigned short vv[16];
            #pragma unroll
            for (int jj=0;jj<16;jj++) vv[jj] = v_b[(j0 + vjg*16 + jj)*DH + vd];
            #pragma unroll
            for (int hh=0;hh<2;hh++){
                short8 pk;
                #pragma unroll
                for (int e=0;e<8;e++) pk[e] = (short)vv[hh*8+e];
                *(short8*)(&vt_lds[vd*64 + (((vjg*2+hh) ^ (vd&7))<<3)]) = pk;
            }
        }
        __syncthreads();

        // S = Q K^T (4 frags), R = Q ErBand^T (5 frags, per-wave window)
        f32x4 s_acc[4] = {};
        f32x4 r_acc[5] = {};
        __builtin_amdgcn_s_setprio(1);
        #pragma unroll
        for (int kk=0;kk<2;kk++){
            const int sco = ((kk*4+lk4) ^ (lr&7)) << 3;   // swizzled chunk offset
            #pragma unroll
            for (int n=0;n<4;n++){
                short8 kf = *(const short8*)(&k_lds[(n*16+lr)*64 + sco]);
                s_acc[n] = __builtin_amdgcn_mfma_f32_16x16x32_bf16(qf[kk], kf, s_acc[n], 0,0,0);
            }
            #pragma unroll
            for (int fi=0;fi<5;fi++){
                short8 ef = *(const short8*)(&er_lds[((fbase+fi)*16+lr)*64 + sco]);
                r_acc[fi] = __builtin_amdgcn_mfma_f32_16x16x32_bf16(qf[kk], ef, r_acc[fi], 0,0,0);
            }
        }
        __builtin_amdgcn_s_setprio(0);

        // spill R band (wave-private, no barrier): local col = fi*16+lr
        #pragma unroll
        for (int fi=0;fi<5;fi++)
            #pragma unroll
            for (int r=0;r<4;r++)
                rbw[(lk4*4+r)*80 + fi*16 + lr] = f2b(r_acc[fi][r]);

        // online softmax; gather c'_local = 15 - lk4*4 - r + n*16 + lr
        const bool lastt = (t == ntiles-1);
        #pragma unroll
        for (int r=0;r<4;r++){
            const int rr = lk4*4 + r;
            const int li = w*16 + rr;
            const int gi = i0 + li;
            float sv[4];
            float mx = -INFINITY;
            #pragma unroll
            for (int n=0;n<4;n++){
                float s = (s_acc[n][r] + b2f(rbw[rr*80 + 15 - rr + n*16 + lr])) * SCALE;
                if (lastt && (j0 + n*16 + lr > gi)) s = -INFINITY;
                sv[n] = s;
                mx = fmaxf(mx, s);
            }
            #pragma unroll
            for (int msk=1; msk<16; msk<<=1) mx = fmaxf(mx, __shfl_xor(mx, msk));
            float mnew = fmaxf(m_r[r], mx);
            float sfac = __expf(m_r[r] - mnew);
            m_r[r] = mnew;
            float rs = 0.f;
            #pragma unroll
            for (int n=0;n<4;n++){
                float p = __expf(sv[n] - mnew);
                rs += p;
                const int prow = li;
                p_lds[prow*64 + (((n*2 + (lr>>3)) ^ (prow&7))<<3) + (lr&7)] = f2b(p);
            }
            #pragma unroll
            for (int msk=1; msk<16; msk<<=1) rs += __shfl_xor(rs, msk);
            l_r[r] = l_r[r]*sfac + rs;
            #pragma unroll
            for (int n=0;n<4;n++) o_acc[n][r] *= sfac;
        }

        // O += P V   (p and vt rows this wave wrote/needs are wave-private/staged)
        __builtin_amdgcn_s_setprio(1);
        #pragma unroll
        for (int kk=0;kk<2;kk++){
            const int sco = ((kk*4+lk4) ^ (lr&7)) << 3;
            short8 pf = *(const short8*)(&p_lds[(w*16+lr)*64 + sco]);
            #pragma unroll
            for (int n=0;n<4;n++){
                short8 vf = *(const short8*)(&vt_lds[(n*16+lr)*64 + sco]);
                o_acc[n] = __builtin_amdgcn_mfma_f32_16x16x32_bf16(pf, vf, o_acc[n], 0,0,0);
            }
        }
        __builtin_amdgcn_s_setprio(0);
    }
    // epilogue: out[b][i][h*64+d] = O / l
    const int b_ = bh >> 4, h = bh & 15;
    #pragma unroll
    for (int n=0;n<4;n++)
        #pragma unroll
        for (int r=0;r<4;r++){
            int li = w*16 + lk4*4 + r;
            int d = n*16 + lr;
            out[(b_*SS + i0 + li)*DM + h*DH + d] = o_acc[n][r] / l_r[r];
        }
}

extern "C" void kernel_launch(void* const* d_in, const int* in_sizes, int n_in,
                              void* d_out, int out_size, void* d_ws, size_t ws_size,
                              hipStream_t stream)
{
    const float* x  = (const float*)d_in[0];
    const float* Wq = (const float*)d_in[1];
    const float* bq = (const float*)d_in[2];
    const float* Wk = (const float*)d_in[3];
    const float* bk = (const float*)d_in[4];
    const float* Wv = (const float*)d_in[5];
    const float* bv = (const float*)d_in[6];
    const float* Er = (const float*)d_in[7];
    float* out = (float*)d_out;
    char* ws = (char*)d_ws;
    unsigned short* xb  = (unsigned short*)(ws);              // 8 MB   x bf16 [4096][1024]
    unsigned short* wT  = (unsigned short*)(ws + 8388608);    // 6 MB   W^T bf16 [3072][1024]
    unsigned short* erb = (unsigned short*)(ws + 14680064);   // 144 KB Er bf16 [1152][64] (128 zero rows)
    unsigned short* Qb  = (unsigned short*)(ws + 14827520);   // 8 MB   Q bf16 [b][h][s][d]
    unsigned short* Kb  = (unsigned short*)(ws + 23216128);   // 8 MB
    unsigned short* Vb  = (unsigned short*)(ws + 31604736);   // 8 MB

    cast_f32_bf16_k<<<4096, 256, 0, stream>>>(x, xb);
    cast_f32_bf16_k<<<64, 256, 0, stream>>>(Er, erb);
    hipMemsetAsync(erb + 1024*DH, 0, 128*DH*sizeof(unsigned short), stream);
    transpose_cast_w_k<<<dim3(32,32,3), dim3(32,8), 0, stream>>>(Wq, Wk, Wv, wT);
    gemm_qkv_k<<<dim3(24,32), 256, 0, stream>>>(xb, wT, bq, bk, bv, Qb, Kb, Vb);
    attn_k<<<dim3(64,16), 256, 0, stream>>>(Qb, Kb, Vb, erb, out);
}